// Round 4
// baseline (401.250 us; speedup 1.0000x reference)
//
#include <hip/hip_runtime.h>
#include <hip/hip_bf16.h>
#include <stdint.h>

typedef __attribute__((ext_vector_type(8))) short short8;
typedef __attribute__((ext_vector_type(8))) uint16_t ushort8;
typedef __attribute__((ext_vector_type(4))) float floatx4;

#define TK 32   // K elems per pipeline stage

// ---------- helpers ----------

__device__ __forceinline__ uint16_t f2bf_bits(float f) {
    uint32_t u = __builtin_bit_cast(uint32_t, f);
    u += 0x7FFFu + ((u >> 16) & 1u);
    return (uint16_t)(u >> 16);
}

__device__ __forceinline__ void async_copy16(const void* g, void* l) {
    // global -> LDS direct copy, 16B/lane; LDS dest = wave-uniform base + lane*16
    auto gp = (const __attribute__((address_space(1))) uint32_t*)(uintptr_t)g;
    auto lp = (__attribute__((address_space(3))) uint32_t*)(uint32_t)(uintptr_t)l;
    __builtin_amdgcn_global_load_lds(gp, lp, 16, 0, 0);
}

__device__ __forceinline__ void cvt8_one(const float* __restrict__ s, uint16_t* __restrict__ d) {
    floatx4 a = *(const floatx4*)(s);
    floatx4 b = *(const floatx4*)(s + 4);
    ushort8 o;
#pragma unroll
    for (int k = 0; k < 4; k++) { o[k] = f2bf_bits(a[k]); o[k + 4] = f2bf_bits(b[k]); }
    *(ushort8*)(d) = o;
}

// ---------- conversion / init kernels ----------

__global__ void cvt8(const float* __restrict__ src, uint16_t* __restrict__ dst, int n) {
    int i = (blockIdx.x * 256 + threadIdx.x) * 8;
    if (i < n) cvt8_one(src + i, dst + i);
}

// all three weight tensors in one launch; W2 [51][2048] padded to [64][2048]
__global__ void cvt_weights(const float* __restrict__ W0, const float* __restrict__ W1,
                            const float* __restrict__ W2,
                            uint16_t* __restrict__ o0, uint16_t* __restrict__ o1,
                            uint16_t* __restrict__ o2) {
    int i = (blockIdx.x * 256 + threadIdx.x) * 8;
    if (i < 2097152) {
        cvt8_one(W0 + i, o0 + i);
    } else if (i < 2097152 + 4194304) {
        int j = i - 2097152;
        cvt8_one(W1 + j, o1 + j);
    } else {
        int j = i - 6291456;           // over 64*2048
        if (j < 131072) {
            int row = j >> 11;
            if (row < 51) cvt8_one(W2 + j, o2 + j);
            else { ushort8 z = {0,0,0,0,0,0,0,0}; *(ushort8*)(o2 + j) = z; }
        }
    }
}

// seed d_out[m*51+o] = b2[o]  (split-K layer-2 accumulates on top)
__global__ void init_bias(const float* __restrict__ b2, float* __restrict__ out, int n) {
    int i = blockIdx.x * 256 + threadIdx.x;
    if (i < n) out[i] = b2[i % 51];
}

// ---------- GEMM: C[m,n] (+)= act( sum_k A[m,k]*W[n,k] [+ bias[n]] ) ----------
// A [M,lda] bf16 row-major, W [N,lda] bf16 row-major. 4 waves in 2x2;
// block tile = (MI*32) x (NJ*32); TK=32, DOUBLE-buffered LDS, 1 barrier/iter:
//   barrier -> prefetch(next buf) -> compute(cur buf)
// so the vmcnt(0) drain at each barrier covers loads issued one full compute
// phase earlier (the R3 single-buffer stall).
// LDS swizzle: row of 4x16B groups; slot s holds global group s^((row>>1)&3)
// -> fragment ds_read_b128 lands 2-way max on banks (free, m136).
// SPLITK>1: blockIdx = m_tile*SPLITK + kidx, n0=0, fp32 atomic epilogue
// (bias pre-seeded by init_bias). SPLITK==1: XCD-swizzled (m-slab per XCD).

template <int MI, int NJ, int SPLITK, bool RELU, bool OUTF32, bool ATOMIC>
__global__ __launch_bounds__(256, 2)
void gemm_bt(const uint16_t* __restrict__ A,
             const uint16_t* __restrict__ W,
             const float* __restrict__ bias,
             void* __restrict__ out,
             int M, int N, int lda, int kspan, int ldc, int nstore)
{
    constexpr int TMv = MI * 32;
    constexpr int TNv = NJ * 32;
    constexpr int ACH = TMv / 64;     // 1KB chunks per wave (chunk = 16 rows x 64B)
    constexpr int BCH = TNv / 64;

    __shared__ alignas(16) uint16_t sA[2][TMv * TK];
    __shared__ alignas(16) uint16_t sB[2][TNv * TK];

    const int tid  = threadIdx.x;
    const int wave = tid >> 6;
    const int lane = tid & 63;

    const int f = blockIdx.x;
    int m0, n0, kbeg;
    if constexpr (SPLITK > 1) {
        kbeg = (f % SPLITK) * kspan;   // f&7 == XCD -> each XCD owns one k-slice
        m0   = (f / SPLITK) * TMv;
        n0   = 0;
    } else {
        kbeg = 0;
        const int xcd = f & 7;
        const int loc = f >> 3;
        const int per = (int)gridDim.x >> 3;
        const int nt  = N / TNv;
        n0 = (loc % nt) * TNv;
        m0 = (xcd * (per / nt) + loc / nt) * TMv;
    }

    floatx4 acc[MI][NJ];
    const floatx4 zero = {0.f, 0.f, 0.f, 0.f};
#pragma unroll
    for (int i = 0; i < MI; i++)
#pragma unroll
        for (int j = 0; j < NJ; j++) acc[i][j] = zero;

    const int wr = (wave >> 1) * MI * 16;
    const int wc = (wave & 1) * NJ * 16;

    // staging: chunk = 16 rows x 4 groups(16B); lane -> row lane>>2, slot lane&3
    // slot s stores global group s ^ ((row>>1)&3)
    const int sr   = lane >> 2;
    const int scol = ((lane & 3) ^ ((lane >> 3) & 3)) * 8;

    const uint16_t* ap[ACH];
    const uint16_t* bp[BCH];
#pragma unroll
    for (int t = 0; t < ACH; t++)
        ap[t] = A + (size_t)(m0 + (wave + 4 * t) * 16 + sr) * lda + kbeg + scol;
#pragma unroll
    for (int t = 0; t < BCH; t++)
        bp[t] = W + (size_t)(n0 + (wave + 4 * t) * 16 + sr) * lda + kbeg + scol;

    auto prefetch = [&](int buf) {
#pragma unroll
        for (int t = 0; t < ACH; t++) {
            async_copy16(ap[t], &sA[buf][(wave + 4 * t) * 512]);
            ap[t] += TK;
        }
#pragma unroll
        for (int t = 0; t < BCH; t++) {
            async_copy16(bp[t], &sB[buf][(wave + 4 * t) * 512]);
            bp[t] += TK;
        }
    };

    // fragment: row fm = lane&15, k-group kg = lane>>4, unswizzle slot
    const int fm = lane & 15;
    const int slot = ((lane >> 4) ^ ((fm >> 1) & 3)) * 8;

    auto compute = [&](int buf) {
        short8 af[MI], bfr[NJ];
#pragma unroll
        for (int i = 0; i < MI; i++)
            af[i] = *(const short8*)(&sA[buf][(wr + i * 16 + fm) * TK + slot]);
#pragma unroll
        for (int j = 0; j < NJ; j++)
            bfr[j] = *(const short8*)(&sB[buf][(wc + j * 16 + fm) * TK + slot]);
#pragma unroll
        for (int i = 0; i < MI; i++)
#pragma unroll
            for (int j = 0; j < NJ; j++)
                acc[i][j] = __builtin_amdgcn_mfma_f32_16x16x32_bf16(af[i], bfr[j], acc[i][j], 0, 0, 0);
    };

    const int niter = kspan / TK;      // always even (32 / 64 / 8)
    prefetch(0);
    for (int it = 0; it < niter; it += 2) {
        __syncthreads();               // drains buf0 loads (issued 1 compute ago)
        if (it + 1 < niter) prefetch(1);
        compute(0);
        __syncthreads();               // drains buf1 loads
        if (it + 2 < niter) prefetch(0);
        compute(1);
    }

    // epilogue: C/D layout col = lane&15, row = (lane>>4)*4 + reg
    const int cr = (lane >> 4) * 4;
    const int cc = lane & 15;
#pragma unroll
    for (int i = 0; i < MI; i++) {
        const int gmb = m0 + wr + i * 16 + cr;
#pragma unroll
        for (int j = 0; j < NJ; j++) {
            const int gn = n0 + wc + j * 16 + cc;
            if (gn < nstore) {
                float bv = 0.f;
                if constexpr (!ATOMIC) bv = bias[gn];
#pragma unroll
                for (int r = 0; r < 4; r++) {
                    float v = acc[i][j][r] + bv;
                    if (RELU) v = fmaxf(v, 0.f);
                    const size_t idx = (size_t)(gmb + r) * ldc + gn;
                    if constexpr (ATOMIC)      atomicAdd(&((float*)out)[idx], v);
                    else if constexpr (OUTF32) ((float*)out)[idx] = v;
                    else                       ((uint16_t*)out)[idx] = f2bf_bits(v);
                }
            }
        }
    }
}

// ---------- launch ----------

extern "C" void kernel_launch(void* const* d_in, const int* in_sizes, int n_in,
                              void* d_out, int out_size, void* d_ws, size_t ws_size,
                              hipStream_t stream) {
    (void)in_sizes; (void)n_in; (void)out_size; (void)ws_size;
    const float* X  = (const float*)d_in[1];
    const float* W0 = (const float*)d_in[3];
    const float* b0 = (const float*)d_in[4];
    const float* W1 = (const float*)d_in[5];
    const float* b1 = (const float*)d_in[6];
    const float* W2 = (const float*)d_in[7];
    const float* b2 = (const float*)d_in[8];

    const int M = 16384;     // 16 batches * 1024 pairs

    char* w = (char*)d_ws;
    uint16_t* X0  = (uint16_t*)w; w += (size_t)M * 1024 * 2;
    uint16_t* X1  = (uint16_t*)w; w += (size_t)M * 2048 * 2;
    uint16_t* X2  = (uint16_t*)w; w += (size_t)M * 2048 * 2;
    uint16_t* W0b = (uint16_t*)w; w += (size_t)2048 * 1024 * 2;
    uint16_t* W1b = (uint16_t*)w; w += (size_t)2048 * 2048 * 2;
    uint16_t* W2b = (uint16_t*)w; w += (size_t)64 * 2048 * 2;

    // d_out seeded with bias (layer-2 split-K accumulates atomically on top)
    init_bias<<<(M * 51 + 255) / 256, 256, 0, stream>>>(b2, (float*)d_out, M * 51);
    cvt8<<<M * 1024 / 8 / 256, 256, 0, stream>>>(X, X0, M * 1024);
    cvt_weights<<<(2097152 + 4194304 + 131072) / 8 / 256, 256, 0, stream>>>(
        W0, W1, W2, W0b, W1b, W2b);

    // layer 0: [16384,1024] x [2048,1024]^T -> relu -> bf16; 128x256 tiles
    gemm_bt<4, 8, 1, true, false, false><<<dim3((M / 128) * (2048 / 256)), 256, 0, stream>>>(
        X0, W0b, b0, X1, M, 2048, 1024, 1024, 2048, 2048);
    // layer 1: [16384,2048] x [2048,2048]^T -> relu -> bf16; 128x256 tiles
    gemm_bt<4, 8, 1, true, false, false><<<dim3((M / 128) * (2048 / 256)), 256, 0, stream>>>(
        X1, W1b, b1, X2, M, 2048, 2048, 2048, 2048, 2048);
    // layer 2: [16384,2048] x [64(pad 51),2048]^T, split-K=8, atomic fp32
    gemm_bt<4, 2, 8, false, true, true><<<dim3((M / 128) * 8), 256, 0, stream>>>(
        X2, W2b, nullptr, d_out, M, 64, 2048, 256, 51, 51);
}

// Round 5
// 347.845 us; speedup vs baseline: 1.1535x; 1.1535x over previous
//
#include <hip/hip_runtime.h>
#include <hip/hip_bf16.h>
#include <stdint.h>

typedef __attribute__((ext_vector_type(8))) short short8;
typedef __attribute__((ext_vector_type(8))) uint16_t ushort8;
typedef __attribute__((ext_vector_type(4))) float floatx4;

#define TK 64   // K elems staged per barrier pair

// ---------- helpers ----------

__device__ __forceinline__ uint16_t f2bf_bits(float f) {
    uint32_t u = __builtin_bit_cast(uint32_t, f);
    u += 0x7FFFu + ((u >> 16) & 1u);
    return (uint16_t)(u >> 16);
}

__device__ __forceinline__ void async_copy16(const void* g, void* l) {
    // global -> LDS direct copy, 16B/lane; LDS dest = wave-uniform base + lane*16
    auto gp = (const __attribute__((address_space(1))) uint32_t*)(uintptr_t)g;
    auto lp = (__attribute__((address_space(3))) uint32_t*)(uint32_t)(uintptr_t)l;
    __builtin_amdgcn_global_load_lds(gp, lp, 16, 0, 0);
}

__device__ __forceinline__ void cvt8_one(const float* __restrict__ s, uint16_t* __restrict__ d) {
    floatx4 a = *(const floatx4*)(s);
    floatx4 b = *(const floatx4*)(s + 4);
    ushort8 o;
#pragma unroll
    for (int k = 0; k < 4; k++) { o[k] = f2bf_bits(a[k]); o[k + 4] = f2bf_bits(b[k]); }
    *(ushort8*)(d) = o;
}

// ---------- conversion kernels ----------

__global__ void cvt8(const float* __restrict__ src, uint16_t* __restrict__ dst, int n) {
    int i = (blockIdx.x * 256 + threadIdx.x) * 8;
    if (i < n) cvt8_one(src + i, dst + i);
}

// all three weight tensors in one launch; W2 [51][2048] padded to [64][2048]
__global__ void cvt_weights(const float* __restrict__ W0, const float* __restrict__ W1,
                            const float* __restrict__ W2,
                            uint16_t* __restrict__ o0, uint16_t* __restrict__ o1,
                            uint16_t* __restrict__ o2) {
    int i = (blockIdx.x * 256 + threadIdx.x) * 8;
    if (i < 2097152) {
        cvt8_one(W0 + i, o0 + i);
    } else if (i < 2097152 + 4194304) {
        int j = i - 2097152;
        cvt8_one(W1 + j, o1 + j);
    } else {
        int j = i - 6291456;           // over 64*2048
        if (j < 131072) {
            int row = j >> 11;
            if (row < 51) cvt8_one(W2 + j, o2 + j);
            else { ushort8 z = {0,0,0,0,0,0,0,0}; *(ushort8*)(o2 + j) = z; }
        }
    }
}

// split-K reduction: out[m*51+o] = b2[o] + sum_s part[s][m][o]
__global__ void reduce_out(const float* __restrict__ part, const float* __restrict__ b2,
                           float* __restrict__ out, int M) {
    int idx = blockIdx.x * 256 + threadIdx.x;   // over M*64
    int o = idx & 63;
    if (o < 51) {
        int m = idx >> 6;
        float s = b2[o];
#pragma unroll
        for (int k = 0; k < 8; k++) s += part[(size_t)k * M * 64 + idx];
        out[m * 51 + o] = s;
    }
}

// ---------- GEMM: C[m,n] = act( sum_k A[m,k]*W[n,k] + bias[n] ) ----------
// R3 structure: single-buffered TK=64, 2 barriers/iter, 64 MFMAs/wave between
// barrier pairs. LDS: 1KB chunks of 8 rows x 8 segs(16B); seg slot s holds
// global col-group s ^ (row&7) -> fragment ds_read_b128 is 2-way max (free).
// SPLITK==1: flat grid, XCD swizzle (xcd=f&7 owns contiguous m-slab, n-fast).
// SPLITK>1 (PARTIAL): kidx = f&(SPLITK-1) == XCD -> each XCD streams its own
// disjoint K-stripe of A (L2-resident); plain fp32 stores to per-slice buffer.

template <int MI, int NJ, int SPLITK, bool RELU, bool PARTIAL>
__global__ __launch_bounds__(256, 2)
void gemm_bt(const uint16_t* __restrict__ A,
             const uint16_t* __restrict__ W,
             const float* __restrict__ bias,
             void* __restrict__ out,
             int M, int N, int lda, int kspan, int ldc, int nstore)
{
    constexpr int TMv = MI * 32;
    constexpr int TNv = NJ * 32;
    constexpr int ACH = TMv / 32;     // A 1KB-chunks per wave
    constexpr int BCH = TNv / 32;     // B 1KB-chunks per wave

    __shared__ alignas(16) uint16_t sA[TMv * TK];
    __shared__ alignas(16) uint16_t sB[TNv * TK];

    const int tid  = threadIdx.x;
    const int wave = tid >> 6;
    const int lane = tid & 63;

    const int f = blockIdx.x;
    int m0, n0, kbeg;
    float* opart = (float*)out;
    if constexpr (SPLITK > 1) {
        const int kidx = f & (SPLITK - 1);   // == XCD id -> disjoint K stripes
        kbeg = kidx * kspan;
        m0   = (f >> 3) * TMv;
        n0   = 0;
        opart += (size_t)kidx * M * ldc;
    } else {
        kbeg = 0;
        const int xcd = f & 7;
        const int loc = f >> 3;
        const int per = (int)gridDim.x >> 3;
        const int nt  = N / TNv;
        n0 = (loc % nt) * TNv;
        m0 = (xcd * (per / nt) + loc / nt) * TMv;
    }

    floatx4 acc[MI][NJ];
    const floatx4 zero = {0.f, 0.f, 0.f, 0.f};
#pragma unroll
    for (int i = 0; i < MI; i++)
#pragma unroll
        for (int j = 0; j < NJ; j++) acc[i][j] = zero;

    const int wr = (wave >> 1) * MI * 16;   // wave quadrant row offset
    const int wc = (wave & 1) * NJ * 16;    // wave quadrant col offset

    // staging: chunk = 8 rows x 128B; lane -> row lane>>3, seg (lane&7)^row
    const int sr   = lane >> 3;
    const int scol = ((lane & 7) ^ sr) * 8;   // permuted global col-group

    const uint16_t* ap[ACH];
    const uint16_t* bp[BCH];
#pragma unroll
    for (int t = 0; t < ACH; t++)
        ap[t] = A + (size_t)(m0 + (wave + 4 * t) * 8 + sr) * lda + kbeg + scol;
#pragma unroll
    for (int t = 0; t < BCH; t++)
        bp[t] = W + (size_t)(n0 + (wave + 4 * t) * 8 + sr) * lda + kbeg + scol;

    // fragment addressing: row fm = lane&15, k-group base lane>>4
    const int fm = lane & 15;
    const int fr = fm & 7;                    // row parity for slot unswizzle
    const int kgb = lane >> 4;                // 0..3

    const int niter = kspan / TK;
    for (int it = 0; it < niter; it++) {
#pragma unroll
        for (int t = 0; t < ACH; t++) {
            async_copy16(ap[t], sA + (wave + 4 * t) * 512);
            ap[t] += TK;
        }
#pragma unroll
        for (int t = 0; t < BCH; t++) {
            async_copy16(bp[t], sB + (wave + 4 * t) * 512);
            bp[t] += TK;
        }
        __syncthreads();

#pragma unroll
        for (int kk = 0; kk < 2; kk++) {
            const int slot = ((kgb + 4 * kk) ^ fr) * 8;
            short8 af[MI], bfr[NJ];
#pragma unroll
            for (int i = 0; i < MI; i++)
                af[i] = *(const short8*)(sA + (wr + i * 16 + fm) * TK + slot);
#pragma unroll
            for (int j = 0; j < NJ; j++)
                bfr[j] = *(const short8*)(sB + (wc + j * 16 + fm) * TK + slot);
#pragma unroll
            for (int i = 0; i < MI; i++)
#pragma unroll
                for (int j = 0; j < NJ; j++)
                    acc[i][j] = __builtin_amdgcn_mfma_f32_16x16x32_bf16(af[i], bfr[j], acc[i][j], 0, 0, 0);
        }
        __syncthreads();
    }

    // epilogue: C/D layout col = lane&15, row = (lane>>4)*4 + reg
    const int cr = (lane >> 4) * 4;
    const int cc = lane & 15;
#pragma unroll
    for (int i = 0; i < MI; i++) {
        const int gmb = m0 + wr + i * 16 + cr;
#pragma unroll
        for (int j = 0; j < NJ; j++) {
            const int gn = n0 + wc + j * 16 + cc;
            if (gn < nstore) {
                float bv = 0.f;
                if constexpr (!PARTIAL) bv = bias[gn];
#pragma unroll
                for (int r = 0; r < 4; r++) {
                    float v = acc[i][j][r] + bv;
                    if (RELU) v = fmaxf(v, 0.f);
                    const size_t idx = (size_t)(gmb + r) * ldc + gn;
                    if constexpr (PARTIAL) opart[idx] = v;
                    else                   ((uint16_t*)out)[idx] = f2bf_bits(v);
                }
            }
        }
    }
}

// ---------- launch ----------

extern "C" void kernel_launch(void* const* d_in, const int* in_sizes, int n_in,
                              void* d_out, int out_size, void* d_ws, size_t ws_size,
                              hipStream_t stream) {
    (void)in_sizes; (void)n_in; (void)out_size; (void)ws_size;
    const float* X  = (const float*)d_in[1];
    const float* W0 = (const float*)d_in[3];
    const float* b0 = (const float*)d_in[4];
    const float* W1 = (const float*)d_in[5];
    const float* b1 = (const float*)d_in[6];
    const float* W2 = (const float*)d_in[7];
    const float* b2 = (const float*)d_in[8];

    const int M = 16384;     // 16 batches * 1024 pairs

    char* w = (char*)d_ws;
    uint16_t* X0  = (uint16_t*)w; w += (size_t)M * 1024 * 2;      // 33.5 MB
    uint16_t* X1  = (uint16_t*)w; w += (size_t)M * 2048 * 2;
    uint16_t* X2  = (uint16_t*)w; w += (size_t)M * 2048 * 2;
    uint16_t* W0b = (uint16_t*)w; w += (size_t)2048 * 1024 * 2;
    uint16_t* W1b = (uint16_t*)w; w += (size_t)2048 * 2048 * 2;
    uint16_t* W2b = (uint16_t*)w; w += (size_t)64 * 2048 * 2;
    // layer-2 split-K partials [8][M][64] fp32 = 33.5 MB: alias X0 (dead after L0)
    float* part = (float*)X0;

    cvt8<<<M * 1024 / 8 / 256, 256, 0, stream>>>(X, X0, M * 1024);
    cvt_weights<<<(2097152 + 4194304 + 131072) / 8 / 256, 256, 0, stream>>>(
        W0, W1, W2, W0b, W1b, W2b);

    // layer 0: [16384,1024] x [2048,1024]^T -> relu -> bf16; 128x256 tiles
    gemm_bt<4, 8, 1, true, false><<<dim3((M / 128) * (2048 / 256)), 256, 0, stream>>>(
        X0, W0b, b0, X1, M, 2048, 1024, 1024, 2048, 2048);
    // layer 1: [16384,2048] x [2048,2048]^T -> relu -> bf16; 128x256 tiles
    gemm_bt<4, 8, 1, true, false><<<dim3((M / 128) * (2048 / 256)), 256, 0, stream>>>(
        X1, W1b, b1, X2, M, 2048, 2048, 2048, 2048, 2048);
    // layer 2: [16384,2048] x [64(pad 51),2048]^T, split-K=8 -> fp32 partials
    gemm_bt<4, 2, 8, false, true><<<dim3((M / 128) * 8), 256, 0, stream>>>(
        X2, W2b, nullptr, part, M, 64, 2048, 256, 64, 64);
    // reduce partials + bias -> d_out [16384,51] fp32
    reduce_out<<<M * 64 / 256, 256, 0, stream>>>(part, b2, (float*)d_out, M);
}